// Round 16
// baseline (98.607 us; speedup 1.0000x reference)
//
#include <hip/hip_runtime.h>
#include <hip/hip_bf16.h>
#include <stdint.h>
#include <math.h>

#define NTOK 4096
#define DIM 768
#define FF 3072
#define NE 4
#define MAXGT 40               // max 128-row chunks over all experts (<=35)

typedef __attribute__((ext_vector_type(8))) short bf16x8;
typedef __attribute__((ext_vector_type(4))) float f32x4;
typedef unsigned short u16;

static __device__ __forceinline__ u16 f2bf(float f) {
    union { float f; unsigned u; } c; c.f = f;
    unsigned r = (c.u + 0x7FFFu + ((c.u >> 16) & 1u)) >> 16;
    return (u16)r;
}

// Abramowitz-Stegun 7.1.26, |abs err| <= 1.5e-7
static __device__ __forceinline__ float fast_erff(float x) {
    float ax = fabsf(x);
    float t = 1.0f / (1.0f + 0.3275911f * ax);
    float p = ((((1.061405429f * t - 1.453152027f) * t) + 1.421413741f) * t
               - 0.284496736f) * t + 0.254829592f;
    float y = 1.0f - p * t * __expf(-ax * ax);
    return copysignf(y, x);
}

#define GLD_LDS16(g, l) __builtin_amdgcn_global_load_lds( \
    (const __attribute__((address_space(1))) void*)(g),   \
    (__attribute__((address_space(3))) void*)(l), 16, 0, 0)

// Packed-chunk swizzle: a 128x32 bf16 K-step tile = 8KB chunk of 512 16B-units.
// Element-run (row r, k-chunk c[0..3]) lives at unit j = (r*4 + c) ^ (r&7).

// ---- transpose-pack body: one 64x64 tile of fp32 [K][N] -> packed bf16 chunks ----
static __device__ __forceinline__ void transpose_tile(
    const float* __restrict__ src, u16* __restrict__ dst, float* tile, int tid,
    int cx, int ry, int Ccols, int NSs, int CTs, int e)
{
    const int r0 = ry * 64, c0 = cx * 64;
    #pragma unroll
    for (int p = 0; p < 4; ++p) {
        int f = p * 256 + tid;
        int row = f >> 4, c4 = (f & 15) * 4;
        float4 v = *(const float4*)(src + (size_t)(r0 + row) * Ccols + c0 + c4);
        tile[row * 65 + c4 + 0] = v.x;
        tile[row * 65 + c4 + 1] = v.y;
        tile[row * 65 + c4 + 2] = v.z;
        tile[row * 65 + c4 + 3] = v.w;
    }
    __syncthreads();
    #pragma unroll
    for (int p = 0; p < 2; ++p) {
        int u = p * 256 + tid;
        int orow = u >> 3, g = (u & 7) * 8;
        bf16x8 v;
        #pragma unroll
        for (int j = 0; j < 8; ++j)
            v[j] = (short)f2bf(tile[(g + j) * 65 + orow]);
        const int n = c0 + orow;
        const int ct = n >> 7, rr = n & 127;
        const int k = r0 + g;
        const int t = k >> 5, c = (k >> 3) & 3;
        const int unit = ((rr * 4 + c) ^ (rr & 7));
        *(bf16x8*)(dst + ((size_t)((e * CTs + ct) * NSs + t) << 12) + unit * 8) = v;
    }
}

// ---- K1: W1 transpose (blocks 0..2303)  ||  gate (blocks 2304..3327) ----
__global__ __launch_bounds__(256) void w1gate_kernel(
    const float* __restrict__ W1, const float* __restrict__ x,
    const float* __restrict__ gw, u16* __restrict__ W1tp,
    float* __restrict__ probs, int* __restrict__ eid, u16* __restrict__ xbf)
{
    __shared__ float tile[64 * 65];
    if (blockIdx.x < 2304) {
        const int b2 = blockIdx.x;
        const int e = b2 / 576, rem = b2 % 576;
        transpose_tile(W1 + (size_t)e * DIM * FF, W1tp, tile, threadIdx.x,
                       rem % 48, rem / 48, FF, DIM / 32, FF / 128, e);
        return;
    }
    const int wid = threadIdx.x >> 6, lane = threadIdx.x & 63;
    const int n = (blockIdx.x - 2304) * 4 + wid;
    const float4* xr4 = (const float4*)(x + (size_t)n * DIM);
    float a0 = 0.f, a1 = 0.f, a2 = 0.f, a3 = 0.f;
    float4 xv[3];
    #pragma unroll
    for (int c = 0; c < 3; c++) {
        float4 v = xr4[c * 64 + lane];
        xv[c] = v;
        const float4 g0 = ((const float4*)(gw + 0 * DIM))[c * 64 + lane];
        const float4 g1 = ((const float4*)(gw + 1 * DIM))[c * 64 + lane];
        const float4 g2 = ((const float4*)(gw + 2 * DIM))[c * 64 + lane];
        const float4 g3 = ((const float4*)(gw + 3 * DIM))[c * 64 + lane];
        a0 += v.x * g0.x + v.y * g0.y + v.z * g0.z + v.w * g0.w;
        a1 += v.x * g1.x + v.y * g1.y + v.z * g1.z + v.w * g1.w;
        a2 += v.x * g2.x + v.y * g2.y + v.z * g2.z + v.w * g2.w;
        a3 += v.x * g3.x + v.y * g3.y + v.z * g3.z + v.w * g3.w;
    }
    #pragma unroll
    for (int c = 0; c < 3; c++) {
        ushort4 o;
        o.x = f2bf(xv[c].x); o.y = f2bf(xv[c].y);
        o.z = f2bf(xv[c].z); o.w = f2bf(xv[c].w);
        *(ushort4*)(xbf + (size_t)n * DIM + (c * 64 + lane) * 4) = o;
    }
    #pragma unroll
    for (int off = 32; off > 0; off >>= 1) {
        a0 += __shfl_xor(a0, off);
        a1 += __shfl_xor(a1, off);
        a2 += __shfl_xor(a2, off);
        a3 += __shfl_xor(a3, off);
    }
    if (lane == 0) {
        float l[4] = {a0, a1, a2, a3};
        float m = fmaxf(fmaxf(l[0], l[1]), fmaxf(l[2], l[3]));
        float p[4], s = 0.f;
        #pragma unroll
        for (int e = 0; e < 4; e++) { p[e] = expf(l[e] - m); s += p[e]; }
        float inv = 1.f / s;
        int amax = 0; float best = l[0];
        #pragma unroll
        for (int e = 1; e < 4; e++) if (l[e] > best) { best = l[e]; amax = e; }
        #pragma unroll
        for (int e = 0; e < 4; e++) probs[n * 4 + e] = p[e] * inv;
        eid[n] = amax;
    }
}

// ---- scan: 1 block, 1024 threads, 4 tokens each; deterministic sorted tlist ----
__global__ __launch_bounds__(1024) void scan_kernel(
    const int4* __restrict__ eid4, const float4* __restrict__ probs4,
    int* __restrict__ counts, int* __restrict__ tlist, float* __restrict__ tail)
{
    __shared__ int4 sc[2][1024];
    __shared__ float4 sp[1024];
    const int t = threadIdx.x;
    const int4 e4 = eid4[t];
    int es[4] = {e4.x, e4.y, e4.z, e4.w};
    int c[4] = {0, 0, 0, 0};
    #pragma unroll
    for (int i = 0; i < 4; i++) c[es[i]]++;
    sc[0][t] = make_int4(c[0], c[1], c[2], c[3]);
    float4 ps = probs4[4 * t + 0];
    #pragma unroll
    for (int i = 1; i < 4; i++) {
        float4 v = probs4[4 * t + i];
        ps.x += v.x; ps.y += v.y; ps.z += v.z; ps.w += v.w;
    }
    sp[t] = ps;
    __syncthreads();
    int buf = 0;
    for (int off = 1; off < 1024; off <<= 1) {
        int4 v = sc[buf][t];
        if (t >= off) {
            int4 u = sc[buf][t - off];
            v.x += u.x; v.y += u.y; v.z += u.z; v.w += u.w;
        }
        sc[buf ^ 1][t] = v;
        buf ^= 1;
        __syncthreads();
    }
    const int4 incl = sc[buf][t];
    const int4 tot4 = sc[buf][1023];
    int base[4] = {incl.x - c[0], incl.y - c[1], incl.z - c[2], incl.w - c[3]};
    int run[4] = {0, 0, 0, 0};
    #pragma unroll
    for (int i = 0; i < 4; i++) {
        const int e = es[i];
        tlist[e * NTOK + base[e] + run[e]] = 4 * t + i;
        run[e]++;
    }
    for (int s = 512; s > 0; s >>= 1) {
        if (t < s) {
            float4 a = sp[t], b = sp[t + s];
            a.x += b.x; a.y += b.y; a.z += b.z; a.w += b.w;
            sp[t] = a;
        }
        __syncthreads();
    }
    if (t == 0) {
        int tot[4] = {tot4.x, tot4.y, tot4.z, tot4.w};
        float Ps[4] = {sp[0].x, sp[0].y, sp[0].z, sp[0].w};
        int tb = 0;
        counts[8] = 0;
        float bl = 0.f;
        #pragma unroll
        for (int e = 0; e < 4; e++) {
            counts[e] = tot[e];
            bl += (Ps[e] / (float)NTOK) * ((float)tot[e] / (float)NTOK);
            tb += (tot[e] + 127) >> 7;
            counts[9 + e] = tb;
        }
        tail[0] = bl * (float)NE;
        #pragma unroll
        for (int e = 0; e < 4; e++) tail[1 + e] = (float)tot[e];
    }
}

// ---- gather token rows into packed-swizzled A chunks: [gt][t][8KB] ----
__global__ __launch_bounds__(256) void packA_kernel(
    const u16* __restrict__ xbf, const int* __restrict__ counts,
    const int* __restrict__ tlist, u16* __restrict__ Apack)
{
    const int gt = blockIdx.x >> 3, pp = blockIdx.x & 7;
    const int* tb = counts + 8;
    if (gt >= tb[4]) return;
    const int e = (gt >= tb[1]) + (gt >= tb[2]) + (gt >= tb[3]);
    const int rt = gt - tb[e];
    const int cnt = counts[e];
    for (int u = pp * 1536 + threadIdx.x; u < (pp + 1) * 1536; u += 256) {
        const int t = u >> 9, j = u & 511;
        const int r = ((j >> 3) << 1) | (((j >> 2) & 1) ^ ((j >> 4) & 1));
        const int c = (j & 3) ^ (r & 3);
        const int pos = rt * 128 + r;
        const int tok = tlist[e * NTOK + min(pos, cnt - 1)];
        *(bf16x8*)(Apack + ((size_t)(gt * (DIM / 32) + t) << 12) + j * 8) =
            *(const bf16x8*)(xbf + (size_t)tok * DIM + t * 32 + c * 8);
    }
}

// ---- FUSED: GEMM1 (blocks 0..959)  ||  W2 transpose (blocks 960..2111) ----
// GEMM1: 128x128 tile, 8 waves (2Mx4N, wave 64x32), BK=64, 12 steps,
// 2 LDS bufs x 32KB (2 blk/CU). bias+gelu -> packed-swizzled bf16 hbuf.
__global__ __launch_bounds__(512, 2) void gemm1_w2t_kernel(
    const u16* __restrict__ Apk, const u16* __restrict__ Bpk,
    const float* __restrict__ bias, const int* __restrict__ counts,
    u16* __restrict__ OutP, const float* __restrict__ W2, u16* __restrict__ W2tp)
{
    constexpr int NS = DIM / 64;                 // 12
    constexpr int KC = DIM / 32;                 // 24
    constexpr int CT = FF / 128;                 // 24

    __shared__ __align__(16) u16 L[2][2][2][4096];   // 64 KB (union w/ transpose)

    if (blockIdx.x >= 960) {
        const int half = (threadIdx.x >= 256);
        const int tid = threadIdx.x & 255;
        const int b2 = (blockIdx.x - 960) * 2 + half;
        const int e = b2 / 576, rem = b2 % 576;
        float* tile = (float*)&L[0][0][0][0] + half * (64 * 65);
        transpose_tile(W2 + (size_t)e * DIM * FF, W2tp, tile, tid,
                       rem % 12, rem / 12, DIM, FF / 32, DIM / 128, e);
        return;
    }

    const int gt = blockIdx.x / CT;
    const int ct = blockIdx.x % CT;
    const int* tb = counts + 8;
    if (gt >= tb[4]) return;
    const int e = (gt >= tb[1]) + (gt >= tb[2]) + (gt >= tb[3]);

    const int tid = threadIdx.x, lane = tid & 63, w = tid >> 6;
    const u16* mats[2] = {
        Apk + ((size_t)(gt * KC) << 12),
        Bpk + ((size_t)((e * CT + ct) * KC) << 12)};

    const int wm = w >> 2, wn = w & 3;   // wave = 64x32
    const int fr = lane & 15, fg = lane >> 4;
    const int laneoff = (fr * 64 + fg * 16) ^ ((fr & 7) << 4);

    f32x4 acc[4][2];
    #pragma unroll
    for (int i = 0; i < 4; i++)
        #pragma unroll
        for (int j = 0; j < 2; j++) acc[i][j] = (f32x4){0.f, 0.f, 0.f, 0.f};

    auto stage = [&](int T) {
        const int b = T & 1;
        #pragma unroll
        for (int l = 0; l < 4; ++l) {
            const int s = w * 4 + l;
            const int mat = s >> 4, sub = s & 15, kc = sub >> 3, u8 = sub & 7;
            GLD_LDS16(mats[mat] + ((size_t)(2 * T + kc) << 12) + u8 * 512,
                      &L[b][mat][kc][u8 * 512]);
        }
    };
    auto compute = [&](int T) {
        const int b = T & 1;
        #pragma unroll
        for (int ks = 0; ks < 2; ++ks) {
            const char* LA = (const char*)&L[b][0][ks][0];
            const char* LB = (const char*)&L[b][1][ks][0];
            bf16x8 bg[2];
            #pragma unroll
            for (int n = 0; n < 2; ++n)
                bg[n] = *(const bf16x8*)(LB + (wn * 2 + n) * 1024 + laneoff);
            #pragma unroll
            for (int m = 0; m < 4; ++m) {
                bf16x8 af = *(const bf16x8*)(LA + (wm * 4 + m) * 1024 + laneoff);
                #pragma unroll
                for (int n = 0; n < 2; ++n)
                    acc[m][n] = __builtin_amdgcn_mfma_f32_16x16x32_bf16(
                        af, bg[n], acc[m][n], 0, 0, 0);
            }
        }
    };

    stage(0); stage(1);
    for (int t = 0; t < NS; ++t) {
        if (t < NS - 1)
            asm volatile("s_waitcnt vmcnt(4)" ::: "memory");
        else
            asm volatile("s_waitcnt vmcnt(0)" ::: "memory");
        __builtin_amdgcn_sched_barrier(0);
        __builtin_amdgcn_s_barrier();
        __builtin_amdgcn_sched_barrier(0);
        compute(t);
        __builtin_amdgcn_sched_barrier(0);
        __builtin_amdgcn_s_barrier();
        __builtin_amdgcn_sched_barrier(0);
        if (t + 2 < NS) stage(t + 2);
    }

    #pragma unroll
    for (int m = 0; m < 4; ++m) {
        #pragma unroll
        for (int r2 = 0; r2 < 4; r2++) {
            const int row = wm * 64 + m * 16 + fg * 4 + r2;
            #pragma unroll
            for (int n = 0; n < 2; ++n) {
                const int col = ct * 128 + wn * 32 + n * 16 + fr;
                float v = acc[m][n][r2] + bias[e * FF + col];
                v = 0.5f * v * (1.f + fast_erff(v * 0.70710678118654752f));
                const int unit = ((row * 4 + ((col >> 3) & 3)) ^ (row & 7));
                OutP[((size_t)(gt * (FF / 32) + (col >> 5)) << 12) + unit * 8 +
                     (col & 7)] = f2bf(v);
            }
        }
    }
}

// ---- GEMM2: 128x128, 8 waves, BK=64, K=3072 unsplit, 48 steps ----
// 3 LDS bufs x 32KB = 96KB, 1 blk/CU, single barrier per step + setprio(T5).
__global__ __launch_bounds__(512, 1) void gemm2_kernel(
    const u16* __restrict__ Apk, const u16* __restrict__ Bpk,
    const float* __restrict__ bias, const int* __restrict__ counts,
    const int* __restrict__ tlist, float* __restrict__ out)
{
    constexpr int NS = FF / 64;                  // 48
    constexpr int KC = FF / 32;                  // 96
    constexpr int CT = DIM / 128;                // 6

    const int gt = blockIdx.x / CT;
    const int ct = blockIdx.x % CT;
    const int* tb = counts + 8;
    if (gt >= tb[4]) return;
    const int e = (gt >= tb[1]) + (gt >= tb[2]) + (gt >= tb[3]);
    const int rt = gt - tb[e];
    const int cnt = counts[e];

    __shared__ __align__(16) u16 L[3][2][2][4096];   // 96 KB

    const int tid = threadIdx.x, lane = tid & 63, w = tid >> 6;
    const u16* mats[2] = {
        Apk + ((size_t)(gt * KC) << 12),
        Bpk + ((size_t)((e * CT + ct) * KC) << 12)};

    const int wm = w >> 2, wn = w & 3;
    const int fr = lane & 15, fg = lane >> 4;
    const int laneoff = (fr * 64 + fg * 16) ^ ((fr & 7) << 4);

    f32x4 acc[4][2];
    #pragma unroll
    for (int i = 0; i < 4; i++)
        #pragma unroll
        for (int j = 0; j < 2; j++) acc[i][j] = (f32x4){0.f, 0.f, 0.f, 0.f};

    auto stage = [&](int T) {
        const int b = T % 3;
        #pragma unroll
        for (int l = 0; l < 4; ++l) {
            const int s = w * 4 + l;
            const int mat = s >> 4, sub = s & 15, kc = sub >> 3, u8 = sub & 7;
            GLD_LDS16(mats[mat] + ((size_t)(2 * T + kc) << 12) + u8 * 512,
                      &L[b][mat][kc][u8 * 512]);
        }
    };
    auto compute = [&](int T) {
        const int b = T % 3;
        #pragma unroll
        for (int ks = 0; ks < 2; ++ks) {
            const char* LA = (const char*)&L[b][0][ks][0];
            const char* LB = (const char*)&L[b][1][ks][0];
            bf16x8 bg[2];
            #pragma unroll
            for (int n = 0; n < 2; ++n)
                bg[n] = *(const bf16x8*)(LB + (wn * 2 + n) * 1024 + laneoff);
            #pragma unroll
            for (int m = 0; m < 4; ++m) {
                bf16x8 af = *(const bf16x8*)(LA + (wm * 4 + m) * 1024 + laneoff);
                #pragma unroll
                for (int n = 0; n < 2; ++n)
                    acc[m][n] = __builtin_amdgcn_mfma_f32_16x16x32_bf16(
                        af, bg[n], acc[m][n], 0, 0, 0);
            }
        }
    };

    stage(0); stage(1);                  // 8 loads/wave in flight
    for (int t = 0; t < NS; ++t) {
        if (t < NS - 1)
            asm volatile("s_waitcnt vmcnt(4)" ::: "memory");   // tile t landed
        else
            asm volatile("s_waitcnt vmcnt(0)" ::: "memory");
        __builtin_amdgcn_sched_barrier(0);
        __builtin_amdgcn_s_barrier();
        __builtin_amdgcn_sched_barrier(0);
        if (t + 2 < NS) stage(t + 2);
        __builtin_amdgcn_s_setprio(1);
        compute(t);
        __builtin_amdgcn_s_setprio(0);
    }

    #pragma unroll
    for (int m = 0; m < 4; ++m) {
        #pragma unroll
        for (int r2 = 0; r2 < 4; r2++) {
            const int row = wm * 64 + m * 16 + fg * 4 + r2;
            const int pos = rt * 128 + row;
            if (pos < cnt) {
                const int tok = tlist[e * NTOK + pos];
                #pragma unroll
                for (int n = 0; n < 2; ++n) {
                    const int col = ct * 128 + wn * 32 + n * 16 + fr;
                    out[(size_t)tok * DIM + col] =
                        acc[m][n][r2] + bias[e * DIM + col];
                }
            }
        }
    }
}

extern "C" void kernel_launch(void* const* d_in, const int* in_sizes, int n_in,
                              void* d_out, int out_size, void* d_ws, size_t ws_size,
                              hipStream_t stream) {
    const float* x  = (const float*)d_in[0];
    const float* gw = (const float*)d_in[3];
    const float* W1 = (const float*)d_in[4];
    const float* b1 = (const float*)d_in[5];
    const float* W2 = (const float*)d_in[6];
    const float* b2 = (const float*)d_in[7];
    float* out = (float*)d_out;

    char* ws = (char*)d_ws;
    size_t o = 0;
    auto alloc = [&](size_t bytes) -> void* {
        void* p = ws + o;
        o = (o + bytes + 255) & ~(size_t)255;
        return p;
    };
    u16*   xbf    = (u16*)alloc((size_t)NTOK * DIM * 2);
    u16*   Apack  = (u16*)alloc((size_t)MAXGT * 128 * DIM * 2);
    u16*   W1tp   = (u16*)alloc((size_t)NE * DIM * FF * 2);
    u16*   W2tp   = (u16*)alloc((size_t)NE * DIM * FF * 2);
    u16*   hbuf   = (u16*)alloc((size_t)MAXGT * 128 * FF * 2);
    float* probs  = (float*)alloc((size_t)NTOK * 4 * 4);
    int*   tlist  = (int*)alloc((size_t)NE * NTOK * 4);
    int*   eid    = (int*)alloc((size_t)NTOK * 4);
    int*   counts = (int*)alloc(256);

    // K1: W1 transpose (2304 blocks) || gate (1024 blocks)
    w1gate_kernel<<<2304 + 1024, 256, 0, stream>>>(
        W1, x, gw, W1tp, probs, eid, xbf);
    scan_kernel<<<1, 1024, 0, stream>>>(
        (const int4*)eid, (const float4*)probs, counts, tlist,
        out + (size_t)NTOK * DIM);
    packA_kernel<<<MAXGT * 8, 256, 0, stream>>>(xbf, counts, tlist, Apack);

    // FUSED: GEMM1 (960 blocks) || W2 transpose (1152 blocks, tail-fill)
    gemm1_w2t_kernel<<<960 + 1152, 512, 0, stream>>>(
        Apack, W1tp, b1, counts, hbuf, W2, W2tp);
    // GEMM2: K=3072 unsplit (48 steps), N=768: grid 40*6 = 240, 1 blk/CU, 96KB
    gemm2_kernel<<<MAXGT * (DIM / 128), 512, 0, stream>>>(
        hbuf, W2tp, b2, counts, tlist, out);
}

// Round 17
// 97.369 us; speedup vs baseline: 1.0127x; 1.0127x over previous
//
#include <hip/hip_runtime.h>
#include <hip/hip_bf16.h>
#include <stdint.h>
#include <math.h>

#define NTOK 4096
#define DIM 768
#define FF 3072
#define NE 4
#define MAXGT 40               // max 128-row chunks over all experts (<=35)

typedef __attribute__((ext_vector_type(8))) short bf16x8;
typedef __attribute__((ext_vector_type(4))) float f32x4;
typedef unsigned short u16;

static __device__ __forceinline__ u16 f2bf(float f) {
    union { float f; unsigned u; } c; c.f = f;
    unsigned r = (c.u + 0x7FFFu + ((c.u >> 16) & 1u)) >> 16;
    return (u16)r;
}

// Abramowitz-Stegun 7.1.26, |abs err| <= 1.5e-7
static __device__ __forceinline__ float fast_erff(float x) {
    float ax = fabsf(x);
    float t = 1.0f / (1.0f + 0.3275911f * ax);
    float p = ((((1.061405429f * t - 1.453152027f) * t) + 1.421413741f) * t
               - 0.284496736f) * t + 0.254829592f;
    float y = 1.0f - p * t * __expf(-ax * ax);
    return copysignf(y, x);
}

#define GLD_LDS16(g, l) __builtin_amdgcn_global_load_lds( \
    (const __attribute__((address_space(1))) void*)(g),   \
    (__attribute__((address_space(3))) void*)(l), 16, 0, 0)

// Packed-chunk swizzle: a 128x32 bf16 K-step tile = 8KB chunk of 512 16B-units.
// Element-run (row r, k-chunk c[0..3]) lives at unit j = (r*4 + c) ^ (r&7).

// ---- transpose-pack body: one 64x64 tile of fp32 [K][N] -> packed bf16 chunks ----
static __device__ __forceinline__ void transpose_tile(
    const float* __restrict__ src, u16* __restrict__ dst, float* tile, int tid,
    int cx, int ry, int Ccols, int NSs, int CTs, int e)
{
    const int r0 = ry * 64, c0 = cx * 64;
    #pragma unroll
    for (int p = 0; p < 4; ++p) {
        int f = p * 256 + tid;
        int row = f >> 4, c4 = (f & 15) * 4;
        float4 v = *(const float4*)(src + (size_t)(r0 + row) * Ccols + c0 + c4);
        tile[row * 65 + c4 + 0] = v.x;
        tile[row * 65 + c4 + 1] = v.y;
        tile[row * 65 + c4 + 2] = v.z;
        tile[row * 65 + c4 + 3] = v.w;
    }
    __syncthreads();
    #pragma unroll
    for (int p = 0; p < 2; ++p) {
        int u = p * 256 + tid;
        int orow = u >> 3, g = (u & 7) * 8;
        bf16x8 v;
        #pragma unroll
        for (int j = 0; j < 8; ++j)
            v[j] = (short)f2bf(tile[(g + j) * 65 + orow]);
        const int n = c0 + orow;
        const int ct = n >> 7, rr = n & 127;
        const int k = r0 + g;
        const int t = k >> 5, c = (k >> 3) & 3;
        const int unit = ((rr * 4 + c) ^ (rr & 7));
        *(bf16x8*)(dst + ((size_t)((e * CTs + ct) * NSs + t) << 12) + unit * 8) = v;
    }
}

// ---- K1: W1 transpose (blocks 0..2303)  ||  gate (blocks 2304..3327) ----
__global__ __launch_bounds__(256) void w1gate_kernel(
    const float* __restrict__ W1, const float* __restrict__ x,
    const float* __restrict__ gw, u16* __restrict__ W1tp,
    float* __restrict__ probs, int* __restrict__ eid, u16* __restrict__ xbf)
{
    __shared__ float tile[64 * 65];
    if (blockIdx.x < 2304) {
        const int b2 = blockIdx.x;
        const int e = b2 / 576, rem = b2 % 576;
        transpose_tile(W1 + (size_t)e * DIM * FF, W1tp, tile, threadIdx.x,
                       rem % 48, rem / 48, FF, DIM / 32, FF / 128, e);
        return;
    }
    const int wid = threadIdx.x >> 6, lane = threadIdx.x & 63;
    const int n = (blockIdx.x - 2304) * 4 + wid;
    const float4* xr4 = (const float4*)(x + (size_t)n * DIM);
    float a0 = 0.f, a1 = 0.f, a2 = 0.f, a3 = 0.f;
    float4 xv[3];
    #pragma unroll
    for (int c = 0; c < 3; c++) {
        float4 v = xr4[c * 64 + lane];
        xv[c] = v;
        const float4 g0 = ((const float4*)(gw + 0 * DIM))[c * 64 + lane];
        const float4 g1 = ((const float4*)(gw + 1 * DIM))[c * 64 + lane];
        const float4 g2 = ((const float4*)(gw + 2 * DIM))[c * 64 + lane];
        const float4 g3 = ((const float4*)(gw + 3 * DIM))[c * 64 + lane];
        a0 += v.x * g0.x + v.y * g0.y + v.z * g0.z + v.w * g0.w;
        a1 += v.x * g1.x + v.y * g1.y + v.z * g1.z + v.w * g1.w;
        a2 += v.x * g2.x + v.y * g2.y + v.z * g2.z + v.w * g2.w;
        a3 += v.x * g3.x + v.y * g3.y + v.z * g3.z + v.w * g3.w;
    }
    #pragma unroll
    for (int c = 0; c < 3; c++) {
        ushort4 o;
        o.x = f2bf(xv[c].x); o.y = f2bf(xv[c].y);
        o.z = f2bf(xv[c].z); o.w = f2bf(xv[c].w);
        *(ushort4*)(xbf + (size_t)n * DIM + (c * 64 + lane) * 4) = o;
    }
    #pragma unroll
    for (int off = 32; off > 0; off >>= 1) {
        a0 += __shfl_xor(a0, off);
        a1 += __shfl_xor(a1, off);
        a2 += __shfl_xor(a2, off);
        a3 += __shfl_xor(a3, off);
    }
    if (lane == 0) {
        float l[4] = {a0, a1, a2, a3};
        float m = fmaxf(fmaxf(l[0], l[1]), fmaxf(l[2], l[3]));
        float p[4], s = 0.f;
        #pragma unroll
        for (int e = 0; e < 4; e++) { p[e] = expf(l[e] - m); s += p[e]; }
        float inv = 1.f / s;
        int amax = 0; float best = l[0];
        #pragma unroll
        for (int e = 1; e < 4; e++) if (l[e] > best) { best = l[e]; amax = e; }
        #pragma unroll
        for (int e = 0; e < 4; e++) probs[n * 4 + e] = p[e] * inv;
        eid[n] = amax;
    }
}

// ---- scan: 1 block, 256 threads, 16 tokens each; deterministic sorted tlist ----
__global__ __launch_bounds__(256) void scan_kernel(
    const int4* __restrict__ eid4, const float4* __restrict__ probs4,
    int* __restrict__ counts, int* __restrict__ tlist, float* __restrict__ tail)
{
    __shared__ int4 scA[256], scB[256];
    __shared__ float4 sp[256];
    const int t = threadIdx.x;
    int es[16];
    int c[4] = {0, 0, 0, 0};
    #pragma unroll
    for (int i = 0; i < 4; i++) {
        int4 e4 = eid4[t * 4 + i];
        es[i * 4 + 0] = e4.x; es[i * 4 + 1] = e4.y;
        es[i * 4 + 2] = e4.z; es[i * 4 + 3] = e4.w;
    }
    #pragma unroll
    for (int i = 0; i < 16; i++) c[es[i]]++;
    scA[t] = make_int4(c[0], c[1], c[2], c[3]);
    float4 ps = make_float4(0.f, 0.f, 0.f, 0.f);
    #pragma unroll
    for (int i = 0; i < 16; i++) {
        float4 v = probs4[t * 16 + i];
        ps.x += v.x; ps.y += v.y; ps.z += v.z; ps.w += v.w;
    }
    sp[t] = ps;
    __syncthreads();
    int4 *cur = scA, *nxt = scB;
    for (int off = 1; off < 256; off <<= 1) {
        int4 v = cur[t];
        if (t >= off) {
            int4 u = cur[t - off];
            v.x += u.x; v.y += u.y; v.z += u.z; v.w += u.w;
        }
        nxt[t] = v;
        int4* tmp = cur; cur = nxt; nxt = tmp;
        __syncthreads();
    }
    const int4 incl = cur[t];
    const int4 tot4 = cur[255];
    int base[4] = {incl.x - c[0], incl.y - c[1], incl.z - c[2], incl.w - c[3]};
    int run[4] = {0, 0, 0, 0};
    #pragma unroll
    for (int i = 0; i < 16; i++) {
        const int e = es[i];
        tlist[e * NTOK + base[e] + run[e]] = t * 16 + i;
        run[e]++;
    }
    for (int s = 128; s > 0; s >>= 1) {
        if (t < s) {
            float4 a = sp[t], b = sp[t + s];
            a.x += b.x; a.y += b.y; a.z += b.z; a.w += b.w;
            sp[t] = a;
        }
        __syncthreads();
    }
    if (t == 0) {
        int tot[4] = {tot4.x, tot4.y, tot4.z, tot4.w};
        float Ps[4] = {sp[0].x, sp[0].y, sp[0].z, sp[0].w};
        int tb = 0;
        counts[8] = 0;
        float bl = 0.f;
        #pragma unroll
        for (int e = 0; e < 4; e++) {
            counts[e] = tot[e];
            bl += (Ps[e] / (float)NTOK) * ((float)tot[e] / (float)NTOK);
            tb += (tot[e] + 127) >> 7;
            counts[9 + e] = tb;
        }
        tail[0] = bl * (float)NE;
        #pragma unroll
        for (int e = 0; e < 4; e++) tail[1 + e] = (float)tot[e];
    }
}

// ---- gather token rows into packed-swizzled A chunks: [gt][t][8KB] ----
__global__ __launch_bounds__(256) void packA_kernel(
    const u16* __restrict__ xbf, const int* __restrict__ counts,
    const int* __restrict__ tlist, u16* __restrict__ Apack)
{
    const int gt = blockIdx.x >> 3, pp = blockIdx.x & 7;
    const int* tb = counts + 8;
    if (gt >= tb[4]) return;
    const int e = (gt >= tb[1]) + (gt >= tb[2]) + (gt >= tb[3]);
    const int rt = gt - tb[e];
    const int cnt = counts[e];
    for (int u = pp * 1536 + threadIdx.x; u < (pp + 1) * 1536; u += 256) {
        const int t = u >> 9, j = u & 511;
        const int r = ((j >> 3) << 1) | (((j >> 2) & 1) ^ ((j >> 4) & 1));
        const int c = (j & 3) ^ (r & 3);
        const int pos = rt * 128 + r;
        const int tok = tlist[e * NTOK + min(pos, cnt - 1)];
        *(bf16x8*)(Apack + ((size_t)(gt * (DIM / 32) + t) << 12) + j * 8) =
            *(const bf16x8*)(xbf + (size_t)tok * DIM + t * 32 + c * 8);
    }
}

// ---- FUSED: GEMM1 (blocks 0..959)  ||  W2 transpose (blocks 960..2111) ----
// GEMM1: 128x128 tile, 8 waves (2Mx4N, wave 64x32), BK=64, 12 steps,
// 2 LDS bufs x 32KB (2 blk/CU). bias+gelu -> packed-swizzled bf16 hbuf.
__global__ __launch_bounds__(512, 2) void gemm1_w2t_kernel(
    const u16* __restrict__ Apk, const u16* __restrict__ Bpk,
    const float* __restrict__ bias, const int* __restrict__ counts,
    u16* __restrict__ OutP, const float* __restrict__ W2, u16* __restrict__ W2tp)
{
    constexpr int NS = DIM / 64;                 // 12
    constexpr int KC = DIM / 32;                 // 24
    constexpr int CT = FF / 128;                 // 24

    __shared__ __align__(16) u16 L[2][2][2][4096];   // 64 KB (union w/ transpose)

    if (blockIdx.x >= 960) {
        const int half = (threadIdx.x >= 256);
        const int tid = threadIdx.x & 255;
        const int b2 = (blockIdx.x - 960) * 2 + half;
        const int e = b2 / 576, rem = b2 % 576;
        float* tile = (float*)&L[0][0][0][0] + half * (64 * 65);
        transpose_tile(W2 + (size_t)e * DIM * FF, W2tp, tile, tid,
                       rem % 12, rem / 12, DIM, FF / 32, DIM / 128, e);
        return;
    }

    const int gt = blockIdx.x / CT;
    const int ct = blockIdx.x % CT;
    const int* tb = counts + 8;
    if (gt >= tb[4]) return;
    const int e = (gt >= tb[1]) + (gt >= tb[2]) + (gt >= tb[3]);

    const int tid = threadIdx.x, lane = tid & 63, w = tid >> 6;
    const u16* mats[2] = {
        Apk + ((size_t)(gt * KC) << 12),
        Bpk + ((size_t)((e * CT + ct) * KC) << 12)};

    const int wm = w >> 2, wn = w & 3;   // wave = 64x32
    const int fr = lane & 15, fg = lane >> 4;
    const int laneoff = (fr * 64 + fg * 16) ^ ((fr & 7) << 4);

    f32x4 acc[4][2];
    #pragma unroll
    for (int i = 0; i < 4; i++)
        #pragma unroll
        for (int j = 0; j < 2; j++) acc[i][j] = (f32x4){0.f, 0.f, 0.f, 0.f};

    auto stage = [&](int T) {
        const int b = T & 1;
        #pragma unroll
        for (int l = 0; l < 4; ++l) {
            const int s = w * 4 + l;
            const int mat = s >> 4, sub = s & 15, kc = sub >> 3, u8 = sub & 7;
            GLD_LDS16(mats[mat] + ((size_t)(2 * T + kc) << 12) + u8 * 512,
                      &L[b][mat][kc][u8 * 512]);
        }
    };
    auto compute = [&](int T) {
        const int b = T & 1;
        #pragma unroll
        for (int ks = 0; ks < 2; ++ks) {
            const char* LA = (const char*)&L[b][0][ks][0];
            const char* LB = (const char*)&L[b][1][ks][0];
            bf16x8 bg[2];
            #pragma unroll
            for (int n = 0; n < 2; ++n)
                bg[n] = *(const bf16x8*)(LB + (wn * 2 + n) * 1024 + laneoff);
            #pragma unroll
            for (int m = 0; m < 4; ++m) {
                bf16x8 af = *(const bf16x8*)(LA + (wm * 4 + m) * 1024 + laneoff);
                #pragma unroll
                for (int n = 0; n < 2; ++n)
                    acc[m][n] = __builtin_amdgcn_mfma_f32_16x16x32_bf16(
                        af, bg[n], acc[m][n], 0, 0, 0);
            }
        }
    };

    stage(0); stage(1);
    for (int t = 0; t < NS; ++t) {
        if (t < NS - 1)
            asm volatile("s_waitcnt vmcnt(4)" ::: "memory");
        else
            asm volatile("s_waitcnt vmcnt(0)" ::: "memory");
        __builtin_amdgcn_sched_barrier(0);
        __builtin_amdgcn_s_barrier();
        __builtin_amdgcn_sched_barrier(0);
        compute(t);
        __builtin_amdgcn_sched_barrier(0);
        __builtin_amdgcn_s_barrier();
        __builtin_amdgcn_sched_barrier(0);
        if (t + 2 < NS) stage(t + 2);
    }

    #pragma unroll
    for (int m = 0; m < 4; ++m) {
        #pragma unroll
        for (int r2 = 0; r2 < 4; r2++) {
            const int row = wm * 64 + m * 16 + fg * 4 + r2;
            #pragma unroll
            for (int n = 0; n < 2; ++n) {
                const int col = ct * 128 + wn * 32 + n * 16 + fr;
                float v = acc[m][n][r2] + bias[e * FF + col];
                v = 0.5f * v * (1.f + fast_erff(v * 0.70710678118654752f));
                const int unit = ((row * 4 + ((col >> 3) & 3)) ^ (row & 7));
                OutP[((size_t)(gt * (FF / 32) + (col >> 5)) << 12) + unit * 8 +
                     (col & 7)] = f2bf(v);
            }
        }
    }
}

// ---- GEMM2: 128x128, 8 waves, BK=64, K=3072 unsplit, 48 steps ----
// 3 LDS bufs x 32KB = 96KB (grid 240 < 256 CUs -> 1 blk/CU; free headroom).
// Single barrier per step: vmcnt(4) -> barrier -> stage(t+2) -> compute(t).
__global__ __launch_bounds__(512, 1) void gemm2_kernel(
    const u16* __restrict__ Apk, const u16* __restrict__ Bpk,
    const float* __restrict__ bias, const int* __restrict__ counts,
    const int* __restrict__ tlist, float* __restrict__ out)
{
    constexpr int NS = FF / 64;                  // 48
    constexpr int KC = FF / 32;                  // 96
    constexpr int CT = DIM / 128;                // 6

    const int gt = blockIdx.x / CT;
    const int ct = blockIdx.x % CT;
    const int* tb = counts + 8;
    if (gt >= tb[4]) return;
    const int e = (gt >= tb[1]) + (gt >= tb[2]) + (gt >= tb[3]);
    const int rt = gt - tb[e];
    const int cnt = counts[e];

    __shared__ __align__(16) u16 L[3][2][2][4096];   // 96 KB

    const int tid = threadIdx.x, lane = tid & 63, w = tid >> 6;
    const u16* mats[2] = {
        Apk + ((size_t)(gt * KC) << 12),
        Bpk + ((size_t)((e * CT + ct) * KC) << 12)};

    const int wm = w >> 2, wn = w & 3;
    const int fr = lane & 15, fg = lane >> 4;
    const int laneoff = (fr * 64 + fg * 16) ^ ((fr & 7) << 4);

    f32x4 acc[4][2];
    #pragma unroll
    for (int i = 0; i < 4; i++)
        #pragma unroll
        for (int j = 0; j < 2; j++) acc[i][j] = (f32x4){0.f, 0.f, 0.f, 0.f};

    auto stage = [&](int T) {
        const int b = T % 3;
        #pragma unroll
        for (int l = 0; l < 4; ++l) {
            const int s = w * 4 + l;
            const int mat = s >> 4, sub = s & 15, kc = sub >> 3, u8 = sub & 7;
            GLD_LDS16(mats[mat] + ((size_t)(2 * T + kc) << 12) + u8 * 512,
                      &L[b][mat][kc][u8 * 512]);
        }
    };
    auto compute = [&](int T) {
        const int b = T % 3;
        #pragma unroll
        for (int ks = 0; ks < 2; ++ks) {
            const char* LA = (const char*)&L[b][0][ks][0];
            const char* LB = (const char*)&L[b][1][ks][0];
            bf16x8 bg[2];
            #pragma unroll
            for (int n = 0; n < 2; ++n)
                bg[n] = *(const bf16x8*)(LB + (wn * 2 + n) * 1024 + laneoff);
            #pragma unroll
            for (int m = 0; m < 4; ++m) {
                bf16x8 af = *(const bf16x8*)(LA + (wm * 4 + m) * 1024 + laneoff);
                #pragma unroll
                for (int n = 0; n < 2; ++n)
                    acc[m][n] = __builtin_amdgcn_mfma_f32_16x16x32_bf16(
                        af, bg[n], acc[m][n], 0, 0, 0);
            }
        }
    };

    stage(0); stage(1);                  // 8 loads/wave in flight
    for (int t = 0; t < NS; ++t) {
        if (t < NS - 1)
            asm volatile("s_waitcnt vmcnt(4)" ::: "memory");   // tile t landed
        else
            asm volatile("s_waitcnt vmcnt(0)" ::: "memory");
        __builtin_amdgcn_sched_barrier(0);
        __builtin_amdgcn_s_barrier();
        __builtin_amdgcn_sched_barrier(0);
        if (t + 2 < NS) stage(t + 2);
        compute(t);
    }

    #pragma unroll
    for (int m = 0; m < 4; ++m) {
        #pragma unroll
        for (int r2 = 0; r2 < 4; r2++) {
            const int row = wm * 64 + m * 16 + fg * 4 + r2;
            const int pos = rt * 128 + row;
            if (pos < cnt) {
                const int tok = tlist[e * NTOK + pos];
                #pragma unroll
                for (int n = 0; n < 2; ++n) {
                    const int col = ct * 128 + wn * 32 + n * 16 + fr;
                    out[(size_t)tok * DIM + col] =
                        acc[m][n][r2] + bias[e * DIM + col];
                }
            }
        }
    }
}

extern "C" void kernel_launch(void* const* d_in, const int* in_sizes, int n_in,
                              void* d_out, int out_size, void* d_ws, size_t ws_size,
                              hipStream_t stream) {
    const float* x  = (const float*)d_in[0];
    const float* gw = (const float*)d_in[3];
    const float* W1 = (const float*)d_in[4];
    const float* b1 = (const float*)d_in[5];
    const float* W2 = (const float*)d_in[6];
    const float* b2 = (const float*)d_in[7];
    float* out = (float*)d_out;

    char* ws = (char*)d_ws;
    size_t o = 0;
    auto alloc = [&](size_t bytes) -> void* {
        void* p = ws + o;
        o = (o + bytes + 255) & ~(size_t)255;
        return p;
    };
    u16*   xbf    = (u16*)alloc((size_t)NTOK * DIM * 2);
    u16*   Apack  = (u16*)alloc((size_t)MAXGT * 128 * DIM * 2);
    u16*   W1tp   = (u16*)alloc((size_t)NE * DIM * FF * 2);
    u16*   W2tp   = (u16*)alloc((size_t)NE * DIM * FF * 2);
    u16*   hbuf   = (u16*)alloc((size_t)MAXGT * 128 * FF * 2);
    float* probs  = (float*)alloc((size_t)NTOK * 4 * 4);
    int*   tlist  = (int*)alloc((size_t)NE * NTOK * 4);
    int*   eid    = (int*)alloc((size_t)NTOK * 4);
    int*   counts = (int*)alloc(256);

    // K1: W1 transpose (2304 blocks) || gate (1024 blocks)
    w1gate_kernel<<<2304 + 1024, 256, 0, stream>>>(
        W1, x, gw, W1tp, probs, eid, xbf);
    scan_kernel<<<1, 256, 0, stream>>>(
        (const int4*)eid, (const float4*)probs, counts, tlist,
        out + (size_t)NTOK * DIM);
    packA_kernel<<<MAXGT * 8, 256, 0, stream>>>(xbf, counts, tlist, Apack);

    // FUSED: GEMM1 (960 blocks) || W2 transpose (1152 blocks, tail-fill)
    gemm1_w2t_kernel<<<960 + 1152, 512, 0, stream>>>(
        Apack, W1tp, b1, counts, hbuf, W2, W2tp);
    // GEMM2: K=3072 unsplit (48 steps), N=768: grid 40*6 = 240, 1 blk/CU, 96KB
    gemm2_kernel<<<MAXGT * (DIM / 128), 512, 0, stream>>>(
        hbuf, W2tp, b2, counts, tlist, out);
}